// Round 1
// 175.699 us; speedup vs baseline: 1.0043x; 1.0043x over previous
//
#include <hip/hip_runtime.h>
#include <math.h>

// Problem constants
#define Bn    64
#define Cn    3
#define IMG   224
#define PLANE (IMG*IMG)      // 50176
#define C1    6
#define P1    110            // conv1(220) + maxpool2 -> 110
#define P2    106            // conv2 output spatial
#define NVALID (P2*P2)       // 11236
#define Hh    32
#define Ww    64
#define UPR   10
#define UPT   10
#define Hg    (Hh*UPR)       // 320
#define Wg    (Ww*UPT)       // 640
#define POOLED_SIZE (Bn*Cn*Hh*Ww)   // 393216
#define NCHUNK 28            // 28 chunks x 4 pooled rows = 112 >= 110
#define PSTRIDE 152          // padded 150-float partial slot
#define ROWB  (IMG*8)        // 1792 B: one NHWC4-bf16 input row

typedef unsigned short u16;
typedef short s8v __attribute__((ext_vector_type(8)));   // 8 bf16 (4 VGPR) MFMA frag
typedef float f4v __attribute__((ext_vector_type(4)));   // 16x16 MFMA accumulator

// workspace: partials (B*28*152 f32) | wt (B*2 f32) | x4b (B*224*224*4 bf16)
#define PART_FLOATS ((size_t)Bn * NCHUNK * PSTRIDE)     // 272,384
#define X4B_U16     ((size_t)Bn * PLANE * 4)
#define WS_NEEDED   ((PART_FLOATS + Bn * 2) * 4 + X4B_U16 * 2)

__device__ __forceinline__ u16 f2bf(float f) {
    union { unsigned int u; float f; } c; c.f = f;
    unsigned int r = c.u + 0x7fffu + ((c.u >> 16) & 1u);   // RNE
    return (u16)(r >> 16);
}
__device__ __forceinline__ float bf2f(u16 v) {
    union { unsigned int u; float f; } c; c.u = ((unsigned int)v) << 16;
    return c.f;
}

// group-local broadcast: read lane (group_base + idx) of a 16-lane group
#define GSHFL(v, idx) __shfl((v), (lane & 48) + (idx), 64)

// -------------------------------------------------------------------------
// K1 (MFMA): fused conv1 (implicit GEMM on matrix cores, bf16 inputs,
// hi+lo-split bf16 weights for ~fp32 weight accuracy) + maxpool2 +
// bf16-NHWC4 pack + windowed row sums -> per-chunk partials.
//
// Grid (28,64): block = chunk of 4 pooled rows (8 conv rows, 12 input rows).
// The NHWC4-bf16 LDS staging doubles as conv operand AND x4b pack source.
// K-mapping k = ic + 4*kx makes each lane's 8 K-elems one contiguous 16B
// LDS read; A (weights) uses the same (group,j)->k map, so the contraction
// is layout-permutation-proof. Each input-row B-frag feeds up to 5 ky's.
// C-layout (verified): col=lane&15, row=(lane>>4)*4+reg.
// -------------------------------------------------------------------------
__global__ __launch_bounds__(256) void k1_fused(
    const float* __restrict__ x,      // (B,3,224,224)
    const float* __restrict__ w1,     // (6,3,5,5)
    const float* __restrict__ b1,     // (6,)
    float* __restrict__ partial,      // (B,28,PSTRIDE)
    u16* __restrict__ x4b,            // (B,224,224,4) bf16 out
    int do_pack)
{
    __shared__ __attribute__((aligned(16))) unsigned char xs[12 * ROWB + 128];
    __shared__ float rowR[4][C1][4];     // [wave][oc][py]  row-sum partials
    __shared__ float edgeLo[4][C1][4];   // [py][oc][j]  S_{j+1} = sum cols 0..j
    __shared__ float edgeHi[4][C1][4];   // [py][oc][j]  U_{j+1} = sum cols 109-j..109

    const int b     = blockIdx.y;
    const int chunk = blockIdx.x;
    const int tid   = threadIdx.x;
    const int wid   = tid >> 6;
    const int lane  = tid & 63;
    const int n     = lane & 15;      // B col / A row / C col
    const int g     = lane >> 4;      // K-group (and C row-group)
    const int gy0   = chunk * 8;      // first input row of this chunk

    const float* xb = x + (size_t)b * (Cn * PLANE);

    // ---- A fragments: weights, hi+lo bf16 split, k = ic + 4*kx ----
    s8v ahi[5], alo[5];
    #pragma unroll
    for (int ky = 0; ky < 5; ++ky) {
        #pragma unroll
        for (int j = 0; j < 8; ++j) {
            const int kmem = g * 8 + j;
            const int ic = kmem & 3, kx = kmem >> 2;
            float w = 0.0f;
            if (n < C1 && ic < 3 && kx < 5)
                w = w1[((n * 3 + ic) * 5 + ky) * 5 + kx];
            const u16 hb = f2bf(w);
            ahi[ky][j] = (short)hb;
            alo[ky][j] = (short)f2bf(w - bf2f(hb));
        }
    }
    f4v binit;
    #pragma unroll
    for (int e = 0; e < 4; ++e) {
        const int oc = g * 4 + e;
        binit[e] = (oc < C1) ? b1[oc] : 0.0f;
    }

    // ---- staging: fp32 NCHW -> bf16 NHWC4 in LDS (+ x4b pack of owned rows)
    u16* ob = x4b + (size_t)b * PLANE * 4;
    for (int i = tid; i < 12 * 112; i += 256) {
        const int r = i / 112;              // staged row 0..11
        const int p = i - r * 112;          // pixel-pair 0..111
        const int gy = gy0 + r;
        uint4 U; U.x = U.y = U.z = U.w = 0u;
        if (gy < IMG) {
            const float2 v0 = *(const float2*)(xb + 0 * PLANE + gy * IMG + 2 * p);
            const float2 v1 = *(const float2*)(xb + 1 * PLANE + gy * IMG + 2 * p);
            const float2 v2 = *(const float2*)(xb + 2 * PLANE + gy * IMG + 2 * p);
            U.x = (unsigned)f2bf(v0.x) | ((unsigned)f2bf(v1.x) << 16);
            U.y = (unsigned)f2bf(v2.x);
            U.z = (unsigned)f2bf(v0.y) | ((unsigned)f2bf(v1.y) << 16);
            U.w = (unsigned)f2bf(v2.y);
        }
        *(uint4*)(xs + r * ROWB + p * 16) = U;
        if (do_pack && r < 8)               // rows gy0..gy0+7 owned (all < 224)
            *(uint4*)(ob + ((size_t)gy * IMG + 2 * p) * 4) = U;
    }
    __syncthreads();

    // ---- conv via MFMA: waves own strips {wid, wid+4, wid+8, wid+12} ----
    float colsum[4][4];
    #pragma unroll
    for (int py = 0; py < 4; ++py)
        #pragma unroll
        for (int e = 0; e < 4; ++e) colsum[py][e] = 0.0f;

    for (int si = 0; si < 4; ++si) {
        const int s = wid + 4 * si;         // strip: conv cols s*16 .. s*16+15
        if (s >= 14) break;
        const unsigned sByte = (unsigned)(s * 128 + n * 8 + g * 16);

        f4v acc[8];
        #pragma unroll
        for (int q = 0; q < 8; ++q) acc[q] = binit;

        #pragma unroll
        for (int r = 0; r < 12; ++r) {
            s8v bf;
            const unsigned char* bp = xs + r * ROWB + sByte;
            ((unsigned long long*)&bf)[0] = *(const unsigned long long*)bp;
            ((unsigned long long*)&bf)[1] = *(const unsigned long long*)(bp + 8);
            #pragma unroll
            for (int ky = 0; ky < 5; ++ky) {          // hi pass
                const int q = r - ky;
                if (q >= 0 && q < 8)
                    acc[q] = __builtin_amdgcn_mfma_f32_16x16x32_bf16(
                        ahi[ky], bf, acc[q], 0, 0, 0);
            }
            #pragma unroll
            for (int ky = 0; ky < 5; ++ky) {          // lo pass (weight residual)
                const int q = r - ky;
                if (q >= 0 && q < 8)
                    acc[q] = __builtin_amdgcn_mfma_f32_16x16x32_bf16(
                        alo[ky], bf, acc[q], 0, 0, 0);
            }
        }

        // maxpool 2x2 + edge capture + col accumulation
        #pragma unroll
        for (int py = 0; py < 4; ++py) {
            #pragma unroll
            for (int e = 0; e < 4; ++e) {
                float t = fmaxf(acc[2 * py][e], acc[2 * py + 1][e]);
                t = fmaxf(t, __shfl_xor(t, 1, 64));   // pair lanes = same pooled col
                if (s == 13 && n >= 12) t = 0.0f;     // junk cols 110,111
                colsum[py][e] += t;
                const int oc = g * 4 + e;
                if (s == 0) {                          // pooled cols 0..3 live here
                    const float c0 = GSHFL(t, 0), c1 = GSHFL(t, 2);
                    const float c2 = GSHFL(t, 4), c3 = GSHFL(t, 6);
                    const float S1 = c0, S2 = S1 + c1, S3 = S2 + c2, S4 = S3 + c3;
                    const float sv = (n == 0) ? S1 : (n == 1) ? S2 : (n == 2) ? S3 : S4;
                    if (n < 4 && oc < C1) edgeLo[py][oc][n] = sv;
                }
                if (s == 13) {                         // pooled cols 106..109 here
                    const float d109 = GSHFL(t, 10), d108 = GSHFL(t, 8);
                    const float d107 = GSHFL(t, 6),  d106 = GSHFL(t, 4);
                    const float U1 = d109, U2 = U1 + d108, U3 = U2 + d107, U4 = U3 + d106;
                    const float uv = (n == 0) ? U1 : (n == 1) ? U2 : (n == 2) ? U3 : U4;
                    if (n < 4 && oc < C1) edgeHi[py][oc][n] = uv;
                }
            }
        }
    }

    // per-wave row sums: reduce 8 same-parity lanes (each pooled col once)
    #pragma unroll
    for (int py = 0; py < 4; ++py) {
        #pragma unroll
        for (int e = 0; e < 4; ++e) {
            float v = colsum[py][e];
            v += __shfl_xor(v, 2, 64);
            v += __shfl_xor(v, 4, 64);
            v += __shfl_xor(v, 8, 64);
            const int oc = g * 4 + e;
            if (n == 0 && oc < C1) rowR[wid][oc][py] = v;
        }
    }
    __syncthreads();

    // final: slot(oc,ky,kx) = sum_py valid(py,ky) * (rowsum - S_kx - U_{4-kx})
    if (tid < 150) {
        const int oc = tid / 25;
        const int rem = tid - oc * 25;
        const int ky = rem / 5, kx = rem - ky * 5;
        float total = 0.0f;
        #pragma unroll
        for (int py = 0; py < 4; ++py) {
            const int y = chunk * 4 + py;
            const bool valid = (y < P1) && ((unsigned)(y - ky) <= 105u);
            float v = rowR[0][oc][py] + rowR[1][oc][py]
                    + rowR[2][oc][py] + rowR[3][oc][py];
            if (kx > 0) v -= edgeLo[py][oc][kx - 1];
            if (kx < 4) v -= edgeHi[py][oc][3 - kx];
            total += valid ? v : 0.0f;
        }
        partial[((size_t)b * NCHUNK + chunk) * PSTRIDE + tid] = total;
    }
}

// -------------------------------------------------------------------------
// K2: reduce partials -> wsum_b; feat = b2 + (W2 . wsum_b)/11236 ;
// fc1+relu ; fc2+sigmoid*5. One block (256 threads) per batch element.
// -------------------------------------------------------------------------
__global__ __launch_bounds__(256) void k2_head(
    const float* __restrict__ partial, const float* __restrict__ w2,
    const float* __restrict__ b2, const float* __restrict__ fc1w,
    const float* __restrict__ fc1b, const float* __restrict__ fc2w,
    const float* __restrict__ fc2b, float* __restrict__ wt_ws,
    float* __restrict__ out)
{
    const int b = blockIdx.x;
    const int tid = threadIdx.x;
    __shared__ float wsb[150];
    __shared__ float sfeat[16];
    __shared__ float sh[8];

    if (tid < 150) {
        const float* p = partial + (size_t)b * NCHUNK * PSTRIDE + tid;
        float s = 0.0f;
        #pragma unroll
        for (int c = 0; c < NCHUNK; ++c) s += p[c * PSTRIDE];
        wsb[tid] = s;
    }
    __syncthreads();
    if (tid < 16) {
        float s = 0.0f;
        for (int j = 0; j < 150; ++j) s += w2[tid * 150 + j] * wsb[j];
        sfeat[tid] = b2[tid] + s * (1.0f / (float)NVALID);
    }
    __syncthreads();
    if (tid < 8) {
        float s = fc1b[tid];
        #pragma unroll
        for (int j = 0; j < 16; ++j) s += fc1w[tid * 16 + j] * sfeat[j];
        sh[tid] = fmaxf(s, 0.0f);
    }
    __syncthreads();
    if (tid < 2) {
        float s = fc2b[tid];
        #pragma unroll
        for (int j = 0; j < 8; ++j) s += fc2w[tid * 8 + j] * sh[j];
        float sig = (s >= 0.0f) ? (1.0f / (1.0f + expf(-s)))
                                : (expf(s) / (1.0f + expf(s)));
        const float wgt = 5.0f * sig;
        wt_ws[b * 2 + tid] = wgt;
        out[POOLED_SIZE + b * 2 + tid] = wgt;
    }
}

// -------------------------------------------------------------------------
// Clamp-coordinate sampling (equivalent to corner-clamp border mode).
// -------------------------------------------------------------------------
__device__ __forceinline__ void sample_coords(
    float gxn, float gyn, int& x0, int& y0, float& wx, float& wy)
{
    float ix = ((gxn + 1.0f) * (float)IMG - 1.0f) * 0.5f;
    float iy = ((gyn + 1.0f) * (float)IMG - 1.0f) * 0.5f;
    ix = fminf(fmaxf(ix, 0.0f), (float)(IMG - 1));
    iy = fminf(fmaxf(iy, 0.0f), (float)(IMG - 1));
    x0 = (int)ix; if (x0 > IMG - 2) x0 = IMG - 2;
    y0 = (int)iy; if (y0 > IMG - 2) y0 = IMG - 2;
    wx = ix - (float)x0;
    wy = iy - (float)y0;
}

// -------------------------------------------------------------------------
// K3 (bf16 NHWC4): log-polar grid sample + 10x10 avg pool.
// XCD-affinity swizzle: b = (L&7) + 8*(L>>8) so one XCD serves 8 images
// (3.2 MB <= 4 MB L2) and walks each image's h-blocks consecutively.
// -------------------------------------------------------------------------
__global__ __launch_bounds__(640) void k3_sample_pool_bf16(
    const u16* __restrict__ x4b,      // (B,224,224,4) bf16
    const float* __restrict__ ltp,
    const float* __restrict__ wt,
    float* __restrict__ out)
{
    __shared__ float part[3 * Wg];

    const int L = blockIdx.x;         // 0..2047
    const int q = L >> 3;             // 0..255
    const int h = q & 31;
    const int b = (L & 7) + 8 * (q >> 5);
    const int tid = threadIdx.x;

    const float w0 = wt[b * 2 + 0];
    const float w1 = wt[b * 2 + 1];
    const float l0 = ltp[b * 2 + 0];
    const float l1 = ltp[b * 2 + 1];
    const float start = logf(0.01f * w0);
    const float stop  = logf(0.6f  * w1);
    const float dr = stop - start;

    const float angle = 6.283185307179586f * (float)tid / (float)Wg;
    const float sn = sinf(angle);
    const float cs = cosf(angle);

    const u16* xb4 = x4b + (size_t)b * PLANE * 4;

    const float ratio = expf(dr * (1.0f / (float)(Hg - 1)));
    float r = expf(start + dr * ((float)(h * UPR) / (float)(Hg - 1)));

    float acc0 = 0.0f, acc1 = 0.0f, acc2 = 0.0f;
    #pragma unroll
    for (int i = 0; i < UPR; ++i) {
        int x0, y0; float wx, wy;
        sample_coords(r * sn + l0, r * cs + l1, x0, y0, wx, wy);
        r *= ratio;

        const u16* base = xb4 + ((size_t)(y0 * IMG + x0)) * 4;
        const ushort4 a00 = *(const ushort4*)(base);
        const ushort4 a01 = *(const ushort4*)(base + 4);
        const ushort4 a10 = *(const ushort4*)(base + IMG * 4);
        const ushort4 a11 = *(const ushort4*)(base + IMG * 4 + 4);

        const float wx0 = 1.0f - wx, wy0 = 1.0f - wy;
        const float w00 = wx0 * wy0, w01 = wx * wy0;
        const float w10 = wx0 * wy,  w11 = wx * wy;

        acc0 += w00*bf2f(a00.x) + w01*bf2f(a01.x) + w10*bf2f(a10.x) + w11*bf2f(a11.x);
        acc1 += w00*bf2f(a00.y) + w01*bf2f(a01.y) + w10*bf2f(a10.y) + w11*bf2f(a11.y);
        acc2 += w00*bf2f(a00.z) + w01*bf2f(a01.z) + w10*bf2f(a10.z) + w11*bf2f(a11.z);
    }
    part[0 * Wg + tid] = acc0;
    part[1 * Wg + tid] = acc1;
    part[2 * Wg + tid] = acc2;
    __syncthreads();

    if (tid < Cn * Ww) {
        const int c = tid / Ww;
        const int w = tid % Ww;
        const float* p = part + c * Wg + w * UPT;
        float s = 0.0f;
        #pragma unroll
        for (int j = 0; j < UPT; ++j) s += p[j];
        out[(((size_t)b * Cn + c) * Hh + h) * Ww + w] = s * (1.0f / (UPR * UPT));
    }
}

// -------------------------------------------------------------------------
// K3 fallback (NCHW fp32 scalar gathers) — only if ws too small for x4b.
// -------------------------------------------------------------------------
__global__ __launch_bounds__(640) void k3_sample_pool_nchw(
    const float* __restrict__ x, const float* __restrict__ ltp,
    const float* __restrict__ wt, float* __restrict__ out)
{
    __shared__ float part[3 * Wg];
    const int L = blockIdx.x;
    const int q = L >> 3;
    const int h = q & 31;
    const int b = (L & 7) + 8 * (q >> 5);
    const int tid = threadIdx.x;

    const float w0 = wt[b * 2 + 0];
    const float w1 = wt[b * 2 + 1];
    const float l0 = ltp[b * 2 + 0];
    const float l1 = ltp[b * 2 + 1];
    const float start = logf(0.01f * w0);
    const float stop  = logf(0.6f  * w1);
    const float dr = stop - start;
    const float angle = 6.283185307179586f * (float)tid / (float)Wg;
    const float sn = sinf(angle);
    const float cs = cosf(angle);
    const float* xb = x + (size_t)b * Cn * PLANE;

    const float ratio = expf(dr * (1.0f / (float)(Hg - 1)));
    float r = expf(start + dr * ((float)(h * UPR) / (float)(Hg - 1)));

    float acc0 = 0.0f, acc1 = 0.0f, acc2 = 0.0f;
    #pragma unroll
    for (int i = 0; i < UPR; ++i) {
        int x0, y0; float wx, wy;
        sample_coords(r * sn + l0, r * cs + l1, x0, y0, wx, wy);
        r *= ratio;
        const float wx0 = 1.0f - wx, wy0 = 1.0f - wy;
        const float w00 = wx0 * wy0, w01 = wx * wy0;
        const float w10 = wx0 * wy,  w11 = wx * wy;
        const int o00 = y0 * IMG + x0;
        acc0 += w00*xb[o00] + w01*xb[o00+1] + w10*xb[o00+IMG] + w11*xb[o00+IMG+1];
        const float* x1p = xb + PLANE;
        acc1 += w00*x1p[o00] + w01*x1p[o00+1] + w10*x1p[o00+IMG] + w11*x1p[o00+IMG+1];
        const float* x2p = xb + 2 * PLANE;
        acc2 += w00*x2p[o00] + w01*x2p[o00+1] + w10*x2p[o00+IMG] + w11*x2p[o00+IMG+1];
    }
    part[0 * Wg + tid] = acc0;
    part[1 * Wg + tid] = acc1;
    part[2 * Wg + tid] = acc2;
    __syncthreads();

    if (tid < Cn * Ww) {
        const int c = tid / Ww;
        const int w = tid % Ww;
        const float* p = part + c * Wg + w * UPT;
        float s = 0.0f;
        #pragma unroll
        for (int j = 0; j < UPT; ++j) s += p[j];
        out[(((size_t)b * Cn + c) * Hh + h) * Ww + w] = s * (1.0f / (UPR * UPT));
    }
}

// -------------------------------------------------------------------------
extern "C" void kernel_launch(void* const* d_in, const int* in_sizes, int n_in,
                              void* d_out, int out_size, void* d_ws, size_t ws_size,
                              hipStream_t stream) {
    const float* x       = (const float*)d_in[0];
    const float* ltp     = (const float*)d_in[1];
    const float* conv1_w = (const float*)d_in[2];
    const float* conv1_b = (const float*)d_in[3];
    const float* conv2_w = (const float*)d_in[4];
    const float* conv2_b = (const float*)d_in[5];
    const float* fc1_w   = (const float*)d_in[6];
    const float* fc1_b   = (const float*)d_in[7];
    const float* fc2_w   = (const float*)d_in[8];
    const float* fc2_b   = (const float*)d_in[9];
    float* out = (float*)d_out;

    const int do_pack = (ws_size >= WS_NEEDED) ? 1 : 0;

    float* part_ws = (float*)d_ws;                // B*28*PSTRIDE
    float* wt_ws   = part_ws + PART_FLOATS;       // B*2
    u16*   x4b     = (u16*)(wt_ws + Bn * 2);      // 8B-aligned

    k1_fused<<<dim3(NCHUNK, Bn), dim3(256), 0, stream>>>(
        x, conv1_w, conv1_b, part_ws, x4b, do_pack);
    k2_head<<<dim3(Bn), dim3(256), 0, stream>>>(part_ws, conv2_w, conv2_b,
                                                fc1_w, fc1_b, fc2_w, fc2_b,
                                                wt_ws, out);
    if (do_pack)
        k3_sample_pool_bf16<<<dim3(Hh * Bn), dim3(Wg), 0, stream>>>(x4b, ltp, wt_ws, out);
    else
        k3_sample_pool_nchw<<<dim3(Hh * Bn), dim3(Wg), 0, stream>>>(x, ltp, wt_ws, out);
}